// Round 9
// baseline (608.526 us; speedup 1.0000x reference)
//
#include <hip/hip_runtime.h>

// Problem constants
#define NW    8192
#define MAXW  20
#define BB    64
#define SS    256
#define CHS   128
#define CHE   64
#define HH    256
#define G3    768
#define WEM   300
#define CAPEM 16

typedef _Float16 half8  __attribute__((ext_vector_type(8)));
typedef _Float16 half4v __attribute__((ext_vector_type(4)));
typedef float    f32x4  __attribute__((ext_vector_type(4)));

// workspace layout (bytes)
#define WF_OFF  0                        // f16 w_hh wave-contig frag-ordered, 2 dirs: 786432 B
#define GI_OFF  (2*G3*HH*2)              // f16 gi table, 2 dirs: 393216 B
#define EMS_OFF (GI_OFF + 2*CHS*G3*2)    // f32 ems, 2 dirs: 16777216 B

__device__ __forceinline__ float fast_sigmoid(float x) {
    float e = __builtin_amdgcn_exp2f(-1.442695041f * x);
    return __builtin_amdgcn_rcpf(1.0f + e);
}
__device__ __forceinline__ float fast_tanh(float x) {
    float e = __builtin_amdgcn_exp2f(2.885390082f * x);
    return 1.0f - 2.0f * __builtin_amdgcn_rcpf(1.0f + e);
}

// Async global->LDS, 16 B per lane. LDS dest is wave-uniform base + lane*16;
// our chunk->lane mapping is constructed to be exactly linear per wave.
__device__ __forceinline__ void gl_lds16(const void* g, void* l) {
    __builtin_amdgcn_global_load_lds(
        (const __attribute__((address_space(1))) void*)g,
        (__attribute__((address_space(3))) void*)l,
        16, 0, 0);
}

// Wave-contiguous fragment layout:
//   Wf halfs: dir*196608 + wv*12288 + g*4096 + kk*512 + (l16*4+q)*8
// A wave's ENTIRE per-step W working set is one contiguous 24 KB block:
// all 24 af loads = one per-thread base + compile-time offsets.
__global__ void prep_w(const float* __restrict__ fw_whh, const float* __restrict__ bw_whh,
                       _Float16* __restrict__ Wf) {
    int dir = blockIdx.x / 48;
    int tile = blockIdx.x % 48;
    int g = tile >> 4, wvv = tile & 15;
    int t = threadIdx.x;                 // 512 = kk(8) * l16(16) * q(4)
    int kk = t >> 6;
    int l16 = (t >> 2) & 15;
    int q = t & 3;
    int m = g * 256 + wvv * 16 + l16;    // row of w_hh
    const float* src = (dir ? bw_whh : fw_whh) + m * HH + kk * 32 + q * 8;
    _Float16* d = Wf + (size_t)dir * G3 * HH
                + (size_t)wvv * 12288 + g * 4096 + kk * 512 + (l16 * 4 + q) * 8;
    #pragma unroll
    for (int j = 0; j < 8; ++j) d[j] = (_Float16)src[j];
}

// gi table (f16): gi[dir][c][j] = sum_e w_ih[j][e]*ch_em[c][e] + b_ih[j] + (j<512 ? b_hh[j] : 0)
__global__ void prep_gi(const float* __restrict__ ch_em,
                        const float* __restrict__ fw_wih, const float* __restrict__ fw_bih,
                        const float* __restrict__ fw_bhh,
                        const float* __restrict__ bw_wih, const float* __restrict__ bw_bih,
                        const float* __restrict__ bw_bhh,
                        _Float16* __restrict__ gi) {
    int bx = blockIdx.x;
    int dir = bx >> 7;
    int c = bx & 127;
    const float* wih = dir ? bw_wih : fw_wih;
    const float* bih = dir ? bw_bih : fw_bih;
    const float* bhh = dir ? bw_bhh : fw_bhh;
    const float* ce = ch_em + c * CHE;
    for (int jj = 0; jj < 3; ++jj) {
        int j = jj * 256 + threadIdx.x;
        float s = bih[j] + (j < 512 ? bhh[j] : 0.0f);
        const float* wr = wih + j * CHE;
        #pragma unroll
        for (int e = 0; e < CHE; ++e) s += wr[e] * ce[e];
        gi[(size_t)dir * CHS * G3 + c * G3 + j] = (_Float16)s;
    }
}

// GRU: 256 blocks (dir*128 + word-block) x 1024 thr (16 waves), 1 block/CU.
//
// Round-9: gate phase evicted from the global path.
// Rounds 6/8 counters: FETCH excess ~500 MB/dispatch = 24 dwords/thread/STEP
// reloaded; WRITE excess ~51 MB = 48 dwords/thread ONCE. Two candidate
// causes, both living in the gate phase's 12 data-dependent global gi loads:
// (H1) LICM'd 64-bit address invariants spilled once, reloaded per step;
// (H2) the gi gather's L2-level volume (503 MB/dispatch) partially missing
// L2. Additionally hbuf32's f32x4 carry accesses were a 16-way bank
// conflict (row stride 1056 B == 8 dwords mod 32 banks) -> bulk of the
// 1.5e7 SQ_LDS_BANK_CONFLICT.
// Fix kills all three at once:
//  - gi staged per step into LDS via global_load_lds (16 B/lane, NO dest
//    VGPRs, issued at loop top, hidden under the MFMA phase, drained by
//    the existing vmcnt(0) before barrier (c)).
//  - TRANSPOSED chunk layout gilds[cch][word]: satisfies the wave-linear
//    LDS-dest constraint of global_load_lds AND makes gate reads
//    word-stride 16 B -> <=4-way conflicts (a row-major copy would be
//    16-way: row stride 1536 B == 0 mod 128 B).
//  - hbuf32 dropped; hprev f32 carry back in 16 regs (affordable: the 12
//    global loads + their address set left the gate phase).
__global__ __launch_bounds__(1024, 4)
void gru(const int* __restrict__ ch, const int* __restrict__ rev_ch,
         const int* __restrict__ wlen,
         const float* __restrict__ fw_bhh, const float* __restrict__ bw_bhh,
         const _Float16* __restrict__ Wf, const _Float16* __restrict__ gi,
         float* __restrict__ ems) {
    int dir = blockIdx.x >> 7;
    int wblk = blockIdx.x & 127;
    int w0 = wblk * 64;
    const int* chp = dir ? rev_ch : ch;
    const _Float16* W = Wf + (size_t)dir * G3 * HH;
    const _Float16* gt = gi + (size_t)dir * CHS * G3;
    const float* bh = dir ? bw_bhh : fw_bhh;
    float* emsd = ems + (size_t)dir * NW * HH;

    int tid = threadIdx.x;
    int wv = tid >> 6;          // 0..15 -> h cols [wv*16, wv*16+16)
    int lane = tid & 63;
    int q = lane >> 4;          // 0..3
    int l16 = lane & 15;

    // This wave's contiguous 24 KB W block; all af loads hang off this base.
    const _Float16* Wme = W + (size_t)wv * 12288 + (l16 * 4 + q) * 8;

    __shared__ __align__(16) _Float16 hbuf[64][264];     // h (f16) for MFMA B-frags
    __shared__ __align__(16) _Float16 gilds[96][64][8];  // step's gi, [chunk][word][16B]
    __shared__ int clds[64][MAXW];                       // chars, staged once
    __shared__ int wls[64];                              // lengths

    // one-time staging
    for (int i = tid; i < 64 * 264; i += 1024) (&hbuf[0][0])[i] = (_Float16)0.0f;
    if (tid < 64) wls[tid] = wlen[w0 + tid];
    for (int i = tid; i < 64 * MAXW; i += 1024) {
        int w = i / MAXW, t = i - w * MAXW;
        clds[w][t] = chp[(w0 + w) * MAXW + t];
    }
    f32x4 bhhn = *(const f32x4*)(bh + 512 + wv * 16 + q * 4);
    const f32x4 fz = {0.0f, 0.0f, 0.0f, 0.0f};
    f32x4 hprev[4] = {fz, fz, fz, fz};
    __syncthreads();

    #pragma unroll 1
    for (int t = 0; t < MAXW; ++t) {
        // (a) stage this step's gi rows: 6144 16B-chunks = 6 x 1024 threads.
        // chunk = it*1024 + tid -> cch = chunk>>6, word = chunk&63; within a
        // wave, dest = gilds + chunk*16 = wave-uniform base + lane*16 (linear,
        // as global_load_lds requires). src = gi row of clds[word][t], 16 B
        // slice cch. No dest VGPRs; drained by vmcnt(0) before barrier (c).
        #pragma unroll
        for (int it = 0; it < 6; ++it) {
            int chunk = it * 1024 + tid;
            int cch = chunk >> 6;
            int word = chunk & 63;
            int c = clds[word][t];
            gl_lds16(gt + (size_t)c * G3 + cch * 8, &gilds[cch][word][0]);
        }

        // (b) MFMA: acc = W_hh x h^T, K = 256 in 8 k-tiles of 32
        f32x4 acc[3][4];
        #pragma unroll
        for (int g = 0; g < 3; ++g)
            #pragma unroll
            for (int ct = 0; ct < 4; ++ct) acc[g][ct] = fz;

        #pragma unroll
        for (int kk = 0; kk < 8; ++kk) {
            half8 af0 = *(const half8*)(Wme + kk * 512);          //  g=0: bytes kk*1024
            half8 af1 = *(const half8*)(Wme + 4096 + kk * 512);   //  g=1: 8 KB + kk*1024
            half8 af2 = *(const half8*)(Wme + 8192 + kk * 512);   //  g=2: 16 KB + kk*1024
            #pragma unroll
            for (int ct = 0; ct < 4; ++ct) {
                half8 bf = *(const half8*)(&hbuf[ct * 16 + l16][kk * 32 + q * 8]);
                acc[0][ct] = __builtin_amdgcn_mfma_f32_16x16x32_f16(af0, bf, acc[0][ct], 0, 0, 0);
                acc[1][ct] = __builtin_amdgcn_mfma_f32_16x16x32_f16(af1, bf, acc[1][ct], 0, 0, 0);
                acc[2][ct] = __builtin_amdgcn_mfma_f32_16x16x32_f16(af2, bf, acc[2][ct], 0, 0, 0);
            }
        }

        __syncthreads();   // (c) hbuf(t-1) reads done; gilds staged & visible

        // (d) elementwise gates + h update; gi from LDS. For gate g, the
        // original halfs offset wv*16 + g*256 + q*4 within the word's row
        // maps to chunk cch = wv*2 + g*32 + (q>>1), sub-offset (q&1)*4.
        // Bank check: dword = 4*(cch*64+word) + (q&1)*2 -> bank
        // (4*l16 + 2*(q&1)) mod 32 -> 4-way (1.58x), vs 16-way row-major.
        {
            int q2 = q >> 1, qo = (q & 1) * 4;
            #pragma unroll
            for (int ct = 0; ct < 4; ++ct) {
                int word = ct * 16 + l16;
                half4v g0 = *(const half4v*)(&gilds[wv * 2 + q2][word][qo]);
                half4v g1 = *(const half4v*)(&gilds[wv * 2 + 32 + q2][word][qo]);
                half4v g2 = *(const half4v*)(&gilds[wv * 2 + 64 + q2][word][qo]);
                f32x4 hv = hprev[ct];
                f32x4 out4;
                half4v hh4;
                #pragma unroll
                for (int e = 0; e < 4; ++e) {
                    float r  = fast_sigmoid(acc[0][ct][e] + (float)g0[e]);
                    float z  = fast_sigmoid(acc[1][ct][e] + (float)g1[e]);
                    float n  = fast_tanh((float)g2[e] + r * (acc[2][ct][e] + bhhn[e]));
                    float hnew = n + z * (hv[e] - n);
                    out4[e] = hnew;
                    hh4[e] = (_Float16)hnew;
                }
                hprev[ct] = out4;
                *(half4v*)(&hbuf[word][wv * 16 + q * 4]) = hh4;
            }
        }
        __syncthreads();   // (e) h(t) complete in hbuf; gilds reads done

        // (f) coalesced ems writeback for words finishing at this step
        {
            int w = tid >> 4, t16 = tid & 15;
            if (wls[w] == t + 1) {
                const _Float16* src = &hbuf[w][t16 * 16];
                half8 a = *(const half8*)(src);
                half8 b = *(const half8*)(src + 8);
                f32x4 o0, o1, o2, o3;
                #pragma unroll
                for (int e = 0; e < 4; ++e) {
                    o0[e] = (float)a[e];     o1[e] = (float)a[4 + e];
                    o2[e] = (float)b[e];     o3[e] = (float)b[4 + e];
                }
                f32x4* dst = (f32x4*)(emsd + (size_t)(w0 + w) * HH + t16 * 16);
                dst[0] = o0; dst[1] = o1; dst[2] = o2; dst[3] = o3;
            }
        }
        // no barrier needed before next (a): gilds(t+1) stores are issued
        // after (e); (d)'s gilds reads completed before (e).
    }
}

// Gather/concat: one block per (b,s) position; 207 f32x4 chunks of 828 f32.
// chunk map: [0,64) pre*m | [64,139) wem | [139,203) suf*m | [203,207) cap
__global__ void emit(const int* __restrict__ w, const int* __restrict__ wcap,
                     const int* __restrict__ wchs, const float* __restrict__ wmask,
                     const float* __restrict__ w_em, const float* __restrict__ cap_em,
                     const float* __restrict__ ems, float* __restrict__ out) {
    int pos = blockIdx.x;
    int c = threadIdx.x;
    if (c >= 207) return;
    int wi = w[pos], cap = wcap[pos], wch = wchs[pos];
    float m = wmask[pos];
    const f32x4* suf = (const f32x4*)(ems + (size_t)wch * HH);                   // fw = suffix
    const f32x4* pre = (const f32x4*)(ems + (size_t)NW * HH + (size_t)wch * HH); // bw = prefix
    const f32x4* wem = (const f32x4*)(w_em + (size_t)wi * WEM);
    const f32x4* cp4 = (const f32x4*)(cap_em + cap * CAPEM);
    f32x4 v;
    if (c < 64)       v = pre[c] * m;
    else if (c < 139) v = wem[c - 64];
    else if (c < 203) v = suf[c - 139] * m;
    else              v = cp4[c - 203];
    ((f32x4*)out)[(size_t)pos * 207 + c] = v;
}

extern "C" void kernel_launch(void* const* d_in, const int* in_sizes, int n_in,
                              void* d_out, int out_size, void* d_ws, size_t ws_size,
                              hipStream_t stream) {
    const int*   ch      = (const int*)d_in[0];
    const int*   rev_ch  = (const int*)d_in[1];
    const int*   w_len   = (const int*)d_in[2];
    const int*   w       = (const int*)d_in[3];
    const int*   w_cap   = (const int*)d_in[4];
    const int*   w_chs   = (const int*)d_in[5];
    const float* w_mask  = (const float*)d_in[6];
    const float* ch_em   = (const float*)d_in[7];
    const float* w_em    = (const float*)d_in[8];
    const float* cap_em  = (const float*)d_in[9];
    const float* fw_wih  = (const float*)d_in[10];
    const float* fw_whh  = (const float*)d_in[11];
    const float* fw_bih  = (const float*)d_in[12];
    const float* fw_bhh  = (const float*)d_in[13];
    const float* bw_wih  = (const float*)d_in[14];
    const float* bw_whh  = (const float*)d_in[15];
    const float* bw_bih  = (const float*)d_in[16];
    const float* bw_bhh  = (const float*)d_in[17];

    char* ws = (char*)d_ws;
    _Float16* Wf = (_Float16*)(ws + WF_OFF);
    _Float16* gi = (_Float16*)(ws + GI_OFF);
    float* ems   = (float*)(ws + EMS_OFF);
    float* out   = (float*)d_out;

    prep_w <<<96, 512, 0, stream>>>(fw_whh, bw_whh, Wf);
    prep_gi<<<256, 256, 0, stream>>>(ch_em, fw_wih, fw_bih, fw_bhh,
                                     bw_wih, bw_bih, bw_bhh, gi);
    gru    <<<256, 1024, 0, stream>>>(ch, rev_ch, w_len, fw_bhh, bw_bhh, Wf, gi, ems);
    emit   <<<BB * SS, 256, 0, stream>>>(w, w_cap, w_chs, w_mask, w_em, cap_em, ems, out);
}

// Round 11
// 462.183 us; speedup vs baseline: 1.3166x; 1.3166x over previous
//
#include <hip/hip_runtime.h>

// Problem constants
#define NW    8192
#define MAXW  20
#define BB    64
#define SS    256
#define CHS   128
#define CHE   64
#define HH    256
#define G3    768
#define WEM   300
#define CAPEM 16

typedef _Float16 half8  __attribute__((ext_vector_type(8)));
typedef _Float16 half4v __attribute__((ext_vector_type(4)));
typedef float    f32x4  __attribute__((ext_vector_type(4)));

// workspace layout (bytes)
#define WF_OFF  0                        // f16 w_hh wave-contig frag-ordered, 2 dirs: 786432 B
#define GI_OFF  (2*G3*HH*2)              // f16 gi table, 2 dirs: 393216 B
#define EMS_OFF (GI_OFF + 2*CHS*G3*2)    // f32 ems, 2 dirs: 16777216 B

__device__ __forceinline__ float fast_sigmoid(float x) {
    float e = __builtin_amdgcn_exp2f(-1.442695041f * x);
    return __builtin_amdgcn_rcpf(1.0f + e);
}
__device__ __forceinline__ float fast_tanh(float x) {
    float e = __builtin_amdgcn_exp2f(2.885390082f * x);
    return 1.0f - 2.0f * __builtin_amdgcn_rcpf(1.0f + e);
}

// VGPR-form MFMA (gfx950 unified file: C/D may be arch VGPRs).
// Forcing "v" constraints keeps the accumulator OUT of the AGPR bank.
// Rationale (R6 vs R7 counters): whenever the MFMA intrinsic puts acc in
// AGPRs, the allocator splits the unified budget EVENLY (128->64+64,
// 256->128+128), leaving the arch side too small for the ~90-value live
// set -> ~24 dwords/thread of loop-invariants spill once and reload every
// t-step -> ~500 MB of L2-thrashing scratch FETCH. With zero AGPR use the
// whole 128-reg budget is one arch pool; demand ~105 fits.
__device__ __forceinline__ void mfma16(f32x4& c, half8 a, half8 b) {
    asm("v_mfma_f32_16x16x32_f16 %0, %1, %2, %0" : "+v"(c) : "v"(a), "v"(b));
}

// Wave-contiguous fragment layout:
//   Wf halfs: dir*196608 + wv*12288 + g*4096 + kk*512 + (l16*4+q)*8
// A wave's ENTIRE per-step W working set is one contiguous 24 KB block:
// all 24 af loads = one per-thread base + compile-time offsets.
__global__ void prep_w(const float* __restrict__ fw_whh, const float* __restrict__ bw_whh,
                       _Float16* __restrict__ Wf) {
    int dir = blockIdx.x / 48;
    int tile = blockIdx.x % 48;
    int g = tile >> 4, wvv = tile & 15;
    int t = threadIdx.x;                 // 512 = kk(8) * l16(16) * q(4)
    int kk = t >> 6;
    int l16 = (t >> 2) & 15;
    int q = t & 3;
    int m = g * 256 + wvv * 16 + l16;    // row of w_hh
    const float* src = (dir ? bw_whh : fw_whh) + m * HH + kk * 32 + q * 8;
    _Float16* d = Wf + (size_t)dir * G3 * HH
                + (size_t)wvv * 12288 + g * 4096 + kk * 512 + (l16 * 4 + q) * 8;
    #pragma unroll
    for (int j = 0; j < 8; ++j) d[j] = (_Float16)src[j];
}

// gi table (f16): gi[dir][c][j] = sum_e w_ih[j][e]*ch_em[c][e] + b_ih[j] + (j<512 ? b_hh[j] : 0)
__global__ void prep_gi(const float* __restrict__ ch_em,
                        const float* __restrict__ fw_wih, const float* __restrict__ fw_bih,
                        const float* __restrict__ fw_bhh,
                        const float* __restrict__ bw_wih, const float* __restrict__ bw_bih,
                        const float* __restrict__ bw_bhh,
                        _Float16* __restrict__ gi) {
    int bx = blockIdx.x;
    int dir = bx >> 7;
    int c = bx & 127;
    const float* wih = dir ? bw_wih : fw_wih;
    const float* bih = dir ? bw_bih : fw_bih;
    const float* bhh = dir ? bw_bhh : fw_bhh;
    const float* ce = ch_em + c * CHE;
    for (int jj = 0; jj < 3; ++jj) {
        int j = jj * 256 + threadIdx.x;
        float s = bih[j] + (j < 512 ? bhh[j] : 0.0f);
        const float* wr = wih + j * CHE;
        #pragma unroll
        for (int e = 0; e < CHE; ++e) s += wr[e] * ce[e];
        gi[(size_t)dir * CHS * G3 + c * G3 + j] = (_Float16)s;
    }
}

// GRU: 256 blocks (dir*128 + word-block) x 1024 thr (16 waves), 1 block/CU.
// Round-11: round-10 resubmitted verbatim (round-10 was an infra failure,
// same signature as rounds 2-4 which later ran clean). Round-6 kernel
// VERBATIM except MFMA emitted in VGPR form via inline asm (see mfma16).
// hprev f32 carry stays in LDS (hbuf32); gi read from L2 in the gate phase
// (data-dependent, not hoistable). Expected: VGPR_Count ~128 (no AGPR
// split), FETCH < 100 MB, dur 309 -> 130-190 us.
__global__ __launch_bounds__(1024, 4)
void gru(const int* __restrict__ ch, const int* __restrict__ rev_ch,
         const int* __restrict__ wlen,
         const float* __restrict__ fw_bhh, const float* __restrict__ bw_bhh,
         const _Float16* __restrict__ Wf, const _Float16* __restrict__ gi,
         float* __restrict__ ems) {
    int dir = blockIdx.x >> 7;
    int wblk = blockIdx.x & 127;
    int w0 = wblk * 64;
    const int* chp = dir ? rev_ch : ch;
    const _Float16* W = Wf + (size_t)dir * G3 * HH;
    const _Float16* gt = gi + (size_t)dir * CHS * G3;
    const float* bh = dir ? bw_bhh : fw_bhh;
    float* emsd = ems + (size_t)dir * NW * HH;

    int tid = threadIdx.x;
    int wv = tid >> 6;          // 0..15 -> h cols [wv*16, wv*16+16)
    int lane = tid & 63;
    int q = lane >> 4;          // 0..3
    int l16 = lane & 15;

    // This wave's contiguous 24 KB W block; all af loads hang off this base.
    const _Float16* Wme = W + (size_t)wv * 12288 + (l16 * 4 + q) * 8;

    __shared__ __align__(16) _Float16 hbuf[64][264];     // h (f16) for MFMA B-frags
    __shared__ __align__(16) float    hbuf32[64][264];   // h (f32) recurrence carry
    __shared__ int clds[64][MAXW];                       // chars, staged once
    __shared__ int wls[64];                              // lengths

    // one-time staging
    for (int i = tid; i < 64 * 264; i += 1024) {
        (&hbuf[0][0])[i] = (_Float16)0.0f;
        (&hbuf32[0][0])[i] = 0.0f;
    }
    if (tid < 64) wls[tid] = wlen[w0 + tid];
    for (int i = tid; i < 64 * MAXW; i += 1024) {
        int w = i / MAXW, t = i - w * MAXW;
        clds[w][t] = chp[(w0 + w) * MAXW + t];
    }
    f32x4 bhhn = *(const f32x4*)(bh + 512 + wv * 16 + q * 4);
    const f32x4 fz = {0.0f, 0.0f, 0.0f, 0.0f};
    __syncthreads();

    #pragma unroll 1
    for (int t = 0; t < MAXW; ++t) {
        // (b) MFMA: acc = W_hh x h^T, K = 256 in 8 k-tiles of 32
        f32x4 acc[3][4];
        #pragma unroll
        for (int g = 0; g < 3; ++g)
            #pragma unroll
            for (int ct = 0; ct < 4; ++ct) acc[g][ct] = fz;

        #pragma unroll
        for (int kk = 0; kk < 8; ++kk) {
            half8 af0 = *(const half8*)(Wme + kk * 512);          //  g=0: bytes kk*1024
            half8 af1 = *(const half8*)(Wme + 4096 + kk * 512);   //  g=1: 8 KB + kk*1024
            half8 af2 = *(const half8*)(Wme + 8192 + kk * 512);   //  g=2: 16 KB + kk*1024
            #pragma unroll
            for (int ct = 0; ct < 4; ++ct) {
                half8 bf = *(const half8*)(&hbuf[ct * 16 + l16][kk * 32 + q * 8]);
                mfma16(acc[0][ct], af0, bf);
                mfma16(acc[1][ct], af1, bf);
                mfma16(acc[2][ct], af2, bf);
            }
        }

        __syncthreads();   // (c) all hbuf(t-1) reads done

        // (d) elementwise gates + h update. gi read from L2 here (addresses
        // are data-dependent -> not hoistable -> no invariant pressure);
        // f32 carry read/written in LDS (one thread per slot, no races).
        #pragma unroll
        for (int ct = 0; ct < 4; ++ct) {
            int word = ct * 16 + l16;
            int c = clds[word][t];
            const _Float16* gr = gt + (size_t)c * G3 + wv * 16 + q * 4;
            half4v g0 = *(const half4v*)(gr);
            half4v g1 = *(const half4v*)(gr + 256);
            half4v g2 = *(const half4v*)(gr + 512);
            f32x4 hv = *(const f32x4*)(&hbuf32[word][wv * 16 + q * 4]);
            f32x4 out4;
            half4v hh4;
            #pragma unroll
            for (int e = 0; e < 4; ++e) {
                float r  = fast_sigmoid(acc[0][ct][e] + (float)g0[e]);
                float z  = fast_sigmoid(acc[1][ct][e] + (float)g1[e]);
                float n  = fast_tanh((float)g2[e] + r * (acc[2][ct][e] + bhhn[e]));
                float hnew = n + z * (hv[e] - n);
                out4[e] = hnew;
                hh4[e] = (_Float16)hnew;
            }
            *(half4v*)(&hbuf[word][wv * 16 + q * 4]) = hh4;
            *(f32x4*)(&hbuf32[word][wv * 16 + q * 4]) = out4;
        }
        __syncthreads();   // (e) h(t) complete in hbuf

        // (f) coalesced ems writeback for words finishing at this step
        {
            int w = tid >> 4, t16 = tid & 15;
            if (wls[w] == t + 1) {
                const _Float16* src = &hbuf[w][t16 * 16];
                half8 a = *(const half8*)(src);
                half8 b = *(const half8*)(src + 8);
                f32x4 o0, o1, o2, o3;
                #pragma unroll
                for (int e = 0; e < 4; ++e) {
                    o0[e] = (float)a[e];     o1[e] = (float)a[4 + e];
                    o2[e] = (float)b[e];     o3[e] = (float)b[4 + e];
                }
                f32x4* dst = (f32x4*)(emsd + (size_t)(w0 + w) * HH + t16 * 16);
                dst[0] = o0; dst[1] = o1; dst[2] = o2; dst[3] = o3;
            }
        }
        // no barrier needed: (f) reads complete before any thread passes next (c)
    }
}

// Gather/concat: one block per (b,s) position; 207 f32x4 chunks of 828 f32.
// chunk map: [0,64) pre*m | [64,139) wem | [139,203) suf*m | [203,207) cap
__global__ void emit(const int* __restrict__ w, const int* __restrict__ wcap,
                     const int* __restrict__ wchs, const float* __restrict__ wmask,
                     const float* __restrict__ w_em, const float* __restrict__ cap_em,
                     const float* __restrict__ ems, float* __restrict__ out) {
    int pos = blockIdx.x;
    int c = threadIdx.x;
    if (c >= 207) return;
    int wi = w[pos], cap = wcap[pos], wch = wchs[pos];
    float m = wmask[pos];
    const f32x4* suf = (const f32x4*)(ems + (size_t)wch * HH);                   // fw = suffix
    const f32x4* pre = (const f32x4*)(ems + (size_t)NW * HH + (size_t)wch * HH); // bw = prefix
    const f32x4* wem = (const f32x4*)(w_em + (size_t)wi * WEM);
    const f32x4* cp4 = (const f32x4*)(cap_em + cap * CAPEM);
    f32x4 v;
    if (c < 64)       v = pre[c] * m;
    else if (c < 139) v = wem[c - 64];
    else if (c < 203) v = suf[c - 139] * m;
    else              v = cp4[c - 203];
    ((f32x4*)out)[(size_t)pos * 207 + c] = v;
}

extern "C" void kernel_launch(void* const* d_in, const int* in_sizes, int n_in,
                              void* d_out, int out_size, void* d_ws, size_t ws_size,
                              hipStream_t stream) {
    const int*   ch      = (const int*)d_in[0];
    const int*   rev_ch  = (const int*)d_in[1];
    const int*   w_len   = (const int*)d_in[2];
    const int*   w       = (const int*)d_in[3];
    const int*   w_cap   = (const int*)d_in[4];
    const int*   w_chs   = (const int*)d_in[5];
    const float* w_mask  = (const float*)d_in[6];
    const float* ch_em   = (const float*)d_in[7];
    const float* w_em    = (const float*)d_in[8];
    const float* cap_em  = (const float*)d_in[9];
    const float* fw_wih  = (const float*)d_in[10];
    const float* fw_whh  = (const float*)d_in[11];
    const float* fw_bih  = (const float*)d_in[12];
    const float* fw_bhh  = (const float*)d_in[13];
    const float* bw_wih  = (const float*)d_in[14];
    const float* bw_whh  = (const float*)d_in[15];
    const float* bw_bih  = (const float*)d_in[16];
    const float* bw_bhh  = (const float*)d_in[17];

    char* ws = (char*)d_ws;
    _Float16* Wf = (_Float16*)(ws + WF_OFF);
    _Float16* gi = (_Float16*)(ws + GI_OFF);
    float* ems   = (float*)(ws + EMS_OFF);
    float* out   = (float*)d_out;

    prep_w <<<96, 512, 0, stream>>>(fw_whh, bw_whh, Wf);
    prep_gi<<<256, 256, 0, stream>>>(ch_em, fw_wih, fw_bih, fw_bhh,
                                     bw_wih, bw_bih, bw_bhh, gi);
    gru    <<<256, 1024, 0, stream>>>(ch, rev_ch, w_len, fw_bhh, bw_bhh, Wf, gi, ems);
    emit   <<<BB * SS, 256, 0, stream>>>(w, w_cap, w_chs, w_mask, w_em, cap_em, ems, out);
}

// Round 12
// 457.683 us; speedup vs baseline: 1.3296x; 1.0098x over previous
//
#include <hip/hip_runtime.h>

// Problem constants
#define NW    8192
#define MAXW  20
#define BB    64
#define SS    256
#define CHS   128
#define CHE   64
#define HH    256
#define G3    768
#define WEM   300
#define CAPEM 16

typedef _Float16 half8  __attribute__((ext_vector_type(8)));
typedef _Float16 half4v __attribute__((ext_vector_type(4)));
typedef float    f32x4  __attribute__((ext_vector_type(4)));

// workspace layout (bytes)
#define WF_OFF  0                        // f16 w_hh wave-contig frag-ordered, 2 dirs: 786432 B
#define GI_OFF  (2*G3*HH*2)              // f16 gi table, 2 dirs: 393216 B
#define EMS_OFF (GI_OFF + 2*CHS*G3*2)    // f32 ems, 2 dirs: 16777216 B

__device__ __forceinline__ float fast_sigmoid(float x) {
    float e = __builtin_amdgcn_exp2f(-1.442695041f * x);
    return __builtin_amdgcn_rcpf(1.0f + e);
}
__device__ __forceinline__ float fast_tanh(float x) {
    float e = __builtin_amdgcn_exp2f(2.885390082f * x);
    return 1.0f - 2.0f * __builtin_amdgcn_rcpf(1.0f + e);
}

// VGPR-form MFMA (gfx950 unified file: C/D in arch VGPRs). Forcing "v"
// constraints keeps the accumulator OUT of the AGPR bank. R11 proof: this
// removed the allocator's even arch/AGPR split (64+64) and with it the
// per-step invariant spill: FETCH 523 MB -> 7.4 MB, gru 309 -> 264 us.
__device__ __forceinline__ void mfma16(f32x4& c, half8 a, half8 b) {
    asm("v_mfma_f32_16x16x32_f16 %0, %1, %2, %0" : "+v"(c) : "v"(a), "v"(b));
}

// Wave-contiguous fragment layout:
//   Wf halfs: dir*196608 + wv*12288 + g*4096 + kk*512 + (l16*4+q)*8
// A wave's ENTIRE per-step W working set is one contiguous 24 KB block.
__global__ void prep_w(const float* __restrict__ fw_whh, const float* __restrict__ bw_whh,
                       _Float16* __restrict__ Wf) {
    int dir = blockIdx.x / 48;
    int tile = blockIdx.x % 48;
    int g = tile >> 4, wvv = tile & 15;
    int t = threadIdx.x;                 // 512 = kk(8) * l16(16) * q(4)
    int kk = t >> 6;
    int l16 = (t >> 2) & 15;
    int q = t & 3;
    int m = g * 256 + wvv * 16 + l16;    // row of w_hh
    const float* src = (dir ? bw_whh : fw_whh) + m * HH + kk * 32 + q * 8;
    _Float16* d = Wf + (size_t)dir * G3 * HH
                + (size_t)wvv * 12288 + g * 4096 + kk * 512 + (l16 * 4 + q) * 8;
    #pragma unroll
    for (int j = 0; j < 8; ++j) d[j] = (_Float16)src[j];
}

// gi table (f16): gi[dir][c][j] = sum_e w_ih[j][e]*ch_em[c][e] + b_ih[j] + (j<512 ? b_hh[j] : 0)
__global__ void prep_gi(const float* __restrict__ ch_em,
                        const float* __restrict__ fw_wih, const float* __restrict__ fw_bih,
                        const float* __restrict__ fw_bhh,
                        const float* __restrict__ bw_wih, const float* __restrict__ bw_bih,
                        const float* __restrict__ bw_bhh,
                        _Float16* __restrict__ gi) {
    int bx = blockIdx.x;
    int dir = bx >> 7;
    int c = bx & 127;
    const float* wih = dir ? bw_wih : fw_wih;
    const float* bih = dir ? bw_bih : fw_bih;
    const float* bhh = dir ? bw_bhh : fw_bhh;
    const float* ce = ch_em + c * CHE;
    for (int jj = 0; jj < 3; ++jj) {
        int j = jj * 256 + threadIdx.x;
        float s = bih[j] + (j < 512 ? bhh[j] : 0.0f);
        const float* wr = wih + j * CHE;
        #pragma unroll
        for (int e = 0; e < CHE; ++e) s += wr[e] * ce[e];
        gi[(size_t)dir * CHS * G3 + c * G3 + j] = (_Float16)s;
    }
}

// GRU: 256 blocks (dir*128 + word-block) x 1024 thr (16 waves), 1 block/CU.
//
// Round-12 (on top of R11's VGPR-form MFMA, which killed the spill):
//  (1) hbuf DOUBLE-BUFFERED -> ONE barrier per step instead of two.
//      h(t) lives in hb[t&1]; MFMA(t) reads hb[(t&1)^1]; gates(t) write
//      hb[t&1]; single barrier; ems writeback reads hb[t&1] after it.
//      Race-free: wave X passes barrier(t) only after its own MFMA(t)
//      reads (program order), so gates(t+1) writes to hb[(t&1)^1] cannot
//      overtake any MFMA(t) read of that buffer.
//  (2) SIX hoisted W base pointers (g x kk-half): every af load is
//      base + compile-time offset <= 3072 B (fits the 13-bit global_load
//      immediate) -> zero per-step address VALU (R11's VALUBusy=31% was
//      dominated by rematerialized 64-bit address math), and the af loads
//      become freely hoistable across the barrier by the scheduler.
//  (3) hprev f32 carry stays in LDS hbuf32 (single copy, per-thread slots).
// LDS total ~140 KB -> still 1 block/CU.
__global__ __launch_bounds__(1024, 4)
void gru(const int* __restrict__ ch, const int* __restrict__ rev_ch,
         const int* __restrict__ wlen,
         const float* __restrict__ fw_bhh, const float* __restrict__ bw_bhh,
         const _Float16* __restrict__ Wf, const _Float16* __restrict__ gi,
         float* __restrict__ ems) {
    int dir = blockIdx.x >> 7;
    int wblk = blockIdx.x & 127;
    int w0 = wblk * 64;
    const int* chp = dir ? rev_ch : ch;
    const _Float16* W = Wf + (size_t)dir * G3 * HH;
    const _Float16* gt = gi + (size_t)dir * CHS * G3;
    const float* bh = dir ? bw_bhh : fw_bhh;
    float* emsd = ems + (size_t)dir * NW * HH;

    int tid = threadIdx.x;
    int wv = tid >> 6;          // 0..15 -> h cols [wv*16, wv*16+16)
    int lane = tid & 63;
    int q = lane >> 4;          // 0..3
    int l16 = lane & 15;

    // Six per-thread invariant W bases; all 24 af loads = base + imm13.
    const _Float16* Wme = W + (size_t)wv * 12288 + (l16 * 4 + q) * 8;
    const _Float16* W00 = Wme;            // g0, kk 0..3
    const _Float16* W01 = Wme + 2048;     // g0, kk 4..7
    const _Float16* W10 = Wme + 4096;     // g1, kk 0..3
    const _Float16* W11 = Wme + 6144;     // g1, kk 4..7
    const _Float16* W20 = Wme + 8192;     // g2, kk 0..3
    const _Float16* W21 = Wme + 10240;    // g2, kk 4..7

    __shared__ __align__(16) _Float16 hbuf[2][64][264];  // h (f16), double-buffered
    __shared__ __align__(16) float    hbuf32[64][264];   // h (f32) recurrence carry
    __shared__ int clds[64][MAXW];                       // chars, staged once
    __shared__ int wls[64];                              // lengths

    // one-time staging: zero hbuf[1] (h(-1)=0 is read at t=0) and hbuf32.
    // hbuf[0] is fully overwritten by gates(0) before any read.
    for (int i = tid; i < 64 * 264; i += 1024) {
        (&hbuf[1][0][0])[i] = (_Float16)0.0f;
        (&hbuf32[0][0])[i] = 0.0f;
    }
    if (tid < 64) wls[tid] = wlen[w0 + tid];
    for (int i = tid; i < 64 * MAXW; i += 1024) {
        int w = i / MAXW, t = i - w * MAXW;
        clds[w][t] = chp[(w0 + w) * MAXW + t];
    }
    f32x4 bhhn = *(const f32x4*)(bh + 512 + wv * 16 + q * 4);
    const f32x4 fz = {0.0f, 0.0f, 0.0f, 0.0f};
    __syncthreads();

    #pragma unroll 1
    for (int t = 0; t < MAXW; ++t) {
        int cu = t & 1;
        _Float16 (*hb_r)[264] = hbuf[cu ^ 1];   // h(t-1)
        _Float16 (*hb_w)[264] = hbuf[cu];       // h(t)

        // (b) MFMA: acc = W_hh x h^T, K = 256 in 8 k-tiles of 32
        f32x4 acc[3][4];
        #pragma unroll
        for (int g = 0; g < 3; ++g)
            #pragma unroll
            for (int ct = 0; ct < 4; ++ct) acc[g][ct] = fz;

        #pragma unroll
        for (int kk = 0; kk < 8; ++kk) {
            int ko = (kk & 3) * 512;            // <= 1536 halfs = 3072 B imm
            half8 af0 = *(const half8*)((kk < 4 ? W00 : W01) + ko);
            half8 af1 = *(const half8*)((kk < 4 ? W10 : W11) + ko);
            half8 af2 = *(const half8*)((kk < 4 ? W20 : W21) + ko);
            #pragma unroll
            for (int ct = 0; ct < 4; ++ct) {
                half8 bf = *(const half8*)(&hb_r[ct * 16 + l16][kk * 32 + q * 8]);
                mfma16(acc[0][ct], af0, bf);
                mfma16(acc[1][ct], af1, bf);
                mfma16(acc[2][ct], af2, bf);
            }
        }

        // (d) elementwise gates + h update; gi from L2 (data-dependent,
        // not hoistable); f32 carry in LDS (per-thread slots, no races).
        // Writes go to hb_w -- MFMA above read hb_r, so no barrier needed
        // between (b) and (d).
        #pragma unroll
        for (int ct = 0; ct < 4; ++ct) {
            int word = ct * 16 + l16;
            int c = clds[word][t];
            const _Float16* gr = gt + (size_t)c * G3 + wv * 16 + q * 4;
            half4v g0 = *(const half4v*)(gr);
            half4v g1 = *(const half4v*)(gr + 256);
            half4v g2 = *(const half4v*)(gr + 512);
            f32x4 hv = *(const f32x4*)(&hbuf32[word][wv * 16 + q * 4]);
            f32x4 out4;
            half4v hh4;
            #pragma unroll
            for (int e = 0; e < 4; ++e) {
                float r  = fast_sigmoid(acc[0][ct][e] + (float)g0[e]);
                float z  = fast_sigmoid(acc[1][ct][e] + (float)g1[e]);
                float n  = fast_tanh((float)g2[e] + r * (acc[2][ct][e] + bhhn[e]));
                float hnew = n + z * (hv[e] - n);
                out4[e] = hnew;
                hh4[e] = (_Float16)hnew;
            }
            *(half4v*)(&hb_w[word][wv * 16 + q * 4]) = hh4;
            *(f32x4*)(&hbuf32[word][wv * 16 + q * 4]) = out4;
        }

        __syncthreads();   // single barrier: h(t) visible; hb_r reads done

        // (f) coalesced ems writeback for words finishing at this step;
        // reads hb_w (= hb[cu]) which gates(t+1) will NOT touch (they
        // write hb[cu^1]) -> safe without a second barrier.
        {
            int w = tid >> 4, t16 = tid & 15;
            if (wls[w] == t + 1) {
                const _Float16* src = &hb_w[w][t16 * 16];
                half8 a = *(const half8*)(src);
                half8 b = *(const half8*)(src + 8);
                f32x4 o0, o1, o2, o3;
                #pragma unroll
                for (int e = 0; e < 4; ++e) {
                    o0[e] = (float)a[e];     o1[e] = (float)a[4 + e];
                    o2[e] = (float)b[e];     o3[e] = (float)b[4 + e];
                }
                f32x4* dst = (f32x4*)(emsd + (size_t)(w0 + w) * HH + t16 * 16);
                dst[0] = o0; dst[1] = o1; dst[2] = o2; dst[3] = o3;
            }
        }
    }
}

// Gather/concat: one block per (b,s) position; 207 f32x4 chunks of 828 f32.
// chunk map: [0,64) pre*m | [64,139) wem | [139,203) suf*m | [203,207) cap
__global__ void emit(const int* __restrict__ w, const int* __restrict__ wcap,
                     const int* __restrict__ wchs, const float* __restrict__ wmask,
                     const float* __restrict__ w_em, const float* __restrict__ cap_em,
                     const float* __restrict__ ems, float* __restrict__ out) {
    int pos = blockIdx.x;
    int c = threadIdx.x;
    if (c >= 207) return;
    int wi = w[pos], cap = wcap[pos], wch = wchs[pos];
    float m = wmask[pos];
    const f32x4* suf = (const f32x4*)(ems + (size_t)wch * HH);                   // fw = suffix
    const f32x4* pre = (const f32x4*)(ems + (size_t)NW * HH + (size_t)wch * HH); // bw = prefix
    const f32x4* wem = (const f32x4*)(w_em + (size_t)wi * WEM);
    const f32x4* cp4 = (const f32x4*)(cap_em + cap * CAPEM);
    f32x4 v;
    if (c < 64)       v = pre[c] * m;
    else if (c < 139) v = wem[c - 64];
    else if (c < 203) v = suf[c - 139] * m;
    else              v = cp4[c - 203];
    ((f32x4*)out)[(size_t)pos * 207 + c] = v;
}

extern "C" void kernel_launch(void* const* d_in, const int* in_sizes, int n_in,
                              void* d_out, int out_size, void* d_ws, size_t ws_size,
                              hipStream_t stream) {
    const int*   ch      = (const int*)d_in[0];
    const int*   rev_ch  = (const int*)d_in[1];
    const int*   w_len   = (const int*)d_in[2];
    const int*   w       = (const int*)d_in[3];
    const int*   w_cap   = (const int*)d_in[4];
    const int*   w_chs   = (const int*)d_in[5];
    const float* w_mask  = (const float*)d_in[6];
    const float* ch_em   = (const float*)d_in[7];
    const float* w_em    = (const float*)d_in[8];
    const float* cap_em  = (const float*)d_in[9];
    const float* fw_wih  = (const float*)d_in[10];
    const float* fw_whh  = (const float*)d_in[11];
    const float* fw_bih  = (const float*)d_in[12];
    const float* fw_bhh  = (const float*)d_in[13];
    const float* bw_wih  = (const float*)d_in[14];
    const float* bw_whh  = (const float*)d_in[15];
    const float* bw_bih  = (const float*)d_in[16];
    const float* bw_bhh  = (const float*)d_in[17];

    char* ws = (char*)d_ws;
    _Float16* Wf = (_Float16*)(ws + WF_OFF);
    _Float16* gi = (_Float16*)(ws + GI_OFF);
    float* ems   = (float*)(ws + EMS_OFF);
    float* out   = (float*)d_out;

    prep_w <<<96, 512, 0, stream>>>(fw_whh, bw_whh, Wf);
    prep_gi<<<256, 256, 0, stream>>>(ch_em, fw_wih, fw_bih, fw_bhh,
                                     bw_wih, bw_bih, bw_bhh, gi);
    gru    <<<256, 1024, 0, stream>>>(ch, rev_ch, w_len, fw_bhh, bw_bhh, Wf, gi, ems);
    emit   <<<BB * SS, 256, 0, stream>>>(w, w_cap, w_chs, w_mask, w_em, cap_em, ems, out);
}